// Round 8
// baseline (856.595 us; speedup 1.0000x reference)
//
#include <hip/hip_runtime.h>
#include <hip/hip_cooperative_groups.h>

namespace cg = cooperative_groups;

#define N_NODES 50000
#define N_EDGES 600000
#define N_GRAPHS 256
#define C 128
#define NB 196            // ceil(N_NODES/256) scan blocks
#define BUILD_BLOCKS 1024
#define BUILD_THREADS (BUILD_BLOCKS * 256)

typedef unsigned short ushort;
typedef unsigned int uint;
typedef __attribute__((ext_vector_type(8))) short bfrag8;
typedef __attribute__((ext_vector_type(4))) float facc4;

// bf16 helpers (bit-level, RNE)
__device__ __forceinline__ ushort f2bf(float v) {
    uint u = __float_as_uint(v);
    u += 0x7FFFu + ((u >> 16) & 1u);
    return (ushort)(u >> 16);
}
__device__ __forceinline__ float bf2f(ushort u) {
    return __uint_as_float(((uint)u) << 16);
}
__device__ __forceinline__ void fsplit(float v, ushort& h, ushort& l) {
    h = f2bf(v);
    l = f2bf(v - bf2f(h));
}

struct WPtrs { const float* wl[4]; const float* wr[4]; };

// ---------------------------------------------------------------- k_build: ONE cooperative kernel replacing
// memset + k_prep + k_scan1 + k_scan2 + k_fill (5 launches + gaps).
// 1024 blocks x 256 threads = exactly 4 blocks/CU co-resident (no LDS,
// low VGPR). Phases separated by grid.sync():
//   Z: zero deg+fill | weight hi/lo split | gstart binary search
//   1: deg atomics over edges (grid-stride)
//   2: scan1 block sums + dinv (blocks 0..195, same code as before)
//   3: scan2 rowptr (blocks 0..195)
//   4: CSR fill (grid-stride)
__global__ __launch_bounds__(256, 4) void k_build(const int* __restrict__ src,
                                                  const int* __restrict__ tgt,
                                                  int* __restrict__ deg,       // deg[50000] + fill[50000] adjacent
                                                  WPtrs wp,
                                                  ushort* __restrict__ BTh,
                                                  ushort* __restrict__ BTl,
                                                  const int* __restrict__ batch,
                                                  int* __restrict__ gstart,
                                                  float* __restrict__ dinv,
                                                  int* __restrict__ rowptr,
                                                  int* __restrict__ csr_src,
                                                  int* __restrict__ bsum) {
    cg::grid_group grid = cg::this_grid();
    __shared__ int ws[4];
    __shared__ int red[4];
    const int b = blockIdx.x, t = threadIdx.x;
    const int gtid = b * 256 + t;
    int* fill = deg + N_NODES;

    // ---- phase Z: zero deg+fill (100000) | wsplit (131072) | gstart (256)
    if (gtid < 2 * N_NODES) {
        deg[gtid] = 0;
    } else if (gtid < 2 * N_NODES + 131072) {
        int gid = gtid - 2 * N_NODES;
        int l = gid >> 15;
        int rem = gid & 32767;
        int n = rem >> 8, k = rem & 255;
        float v = (k < 128) ? wp.wl[l][n * 128 + k] : wp.wr[l][n * 128 + (k - 128)];
        ushort h, lo;
        fsplit(v, h, lo);
        BTh[gid] = h;
        BTl[gid] = lo;
    } else if (gtid < 2 * N_NODES + 131072 + 256) {
        int g = gtid - (2 * N_NODES + 131072);
        int lo = 0, hi = N_NODES;
        while (lo < hi) {
            int mid = (lo + hi) >> 1;
            if (batch[mid] < g) lo = mid + 1;
            else hi = mid;
        }
        gstart[g] = lo;
        if (g == 0) gstart[N_GRAPHS] = N_NODES;
    }
    grid.sync();

    // ---- phase 1: degree atomics
    for (int e = gtid; e < N_EDGES; e += BUILD_THREADS) {
        atomicAdd(&deg[tgt[e]], 1);
    }
    grid.sync();

    // ---- phase 2: scan1 (block sums + dinv), blocks 0..NB-1
    if (b < NB) {
        int idx = b * 256 + t;
        int v = (idx < N_NODES) ? deg[idx] : 0;
        if (idx < N_NODES) dinv[idx] = 1.0f / fmaxf((float)v, 1.0f);
        int s = v;
#pragma unroll
        for (int off = 1; off < 64; off <<= 1) s += __shfl_xor(s, off);
        if ((t & 63) == 0) ws[t >> 6] = s;
        __syncthreads();
        if (t == 0) bsum[b] = ws[0] + ws[1] + ws[2] + ws[3];
    }
    grid.sync();

    // ---- phase 3: scan2 (rowptr), blocks 0..NB-1
    if (b < NB) {
        const int lane = t & 63, w = t >> 6;
        int bv = (t < NB && t < b) ? bsum[t] : 0;
#pragma unroll
        for (int off = 1; off < 64; off <<= 1) bv += __shfl_xor(bv, off);
        if (lane == 0) red[w] = bv;
        __syncthreads();
        const int boff = red[0] + red[1] + red[2] + red[3];
        int idx = b * 256 + t;
        int v = (idx < N_NODES) ? deg[idx] : 0;
        int incl = v;
#pragma unroll
        for (int off = 1; off < 64; off <<= 1) {
            int u = __shfl_up(incl, off);
            if (lane >= off) incl += u;
        }
        if (lane == 63) ws[w] = incl;
        __syncthreads();
        int wo = 0;
        if (w > 0) wo += ws[0];
        if (w > 1) wo += ws[1];
        if (w > 2) wo += ws[2];
        if (idx < N_NODES) rowptr[idx] = boff + wo + incl - v;
        if (b == 0 && t == 0) rowptr[N_NODES] = N_EDGES;
    }
    grid.sync();

    // ---- phase 4: CSR fill
    for (int e = gtid; e < N_EDGES; e += BUILD_THREADS) {
        int d = tgt[e];
        int pos = atomicAdd(&fill[d], 1);
        csr_src[rowptr[d] + pos] = src[e];
    }
}

// ---------------------------------------------------------------- gather-mean, monolithic fp32 (R6 champion body — unchanged)
// FLOOR: per-XCD compulsory misses ~132 MB TCC fetch at ~3.5 TB/s ->
// ~45 us structural. Needs its own high-occupancy launch (R7 lesson:
// at <=8 waves/CU inside a fused kernel this phase degrades ~2x).
__global__ __launch_bounds__(256) void k_gather(const float* __restrict__ Hsrc,
                                                float* __restrict__ AGf,
                                                const int* __restrict__ csr_src,
                                                const int* __restrict__ rowptr,
                                                const float* __restrict__ dinv) {
    int node = blockIdx.x * 8 + (threadIdx.x >> 5);
    if (node >= N_NODES) return;
    int lane = threadIdx.x & 31;
    int c4 = lane << 2;
    int s = rowptr[node], e = rowptr[node + 1];
    float sc = dinv[node];
    float a0 = 0.f, a1 = 0.f, a2 = 0.f, a3 = 0.f;
    int j = s;
    for (; j + 3 < e; j += 4) {
        int s0 = csr_src[j], s1 = csr_src[j + 1];
        int s2 = csr_src[j + 2], s3 = csr_src[j + 3];
        float4 v0 = *(const float4*)(Hsrc + (size_t)s0 * 128 + c4);
        float4 v1 = *(const float4*)(Hsrc + (size_t)s1 * 128 + c4);
        float4 v2 = *(const float4*)(Hsrc + (size_t)s2 * 128 + c4);
        float4 v3 = *(const float4*)(Hsrc + (size_t)s3 * 128 + c4);
        a0 += (v0.x + v1.x) + (v2.x + v3.x);
        a1 += (v0.y + v1.y) + (v2.y + v3.y);
        a2 += (v0.z + v1.z) + (v2.z + v3.z);
        a3 += (v0.w + v1.w) + (v2.w + v3.w);
    }
    for (; j < e; j++) {
        int s0 = csr_src[j];
        float4 v0 = *(const float4*)(Hsrc + (size_t)s0 * 128 + c4);
        a0 += v0.x; a1 += v0.y; a2 += v0.z; a3 += v0.w;
    }
    float4 r; r.x = a0 * sc; r.y = a1 * sc; r.z = a2 * sc; r.w = a3 * sc;
    *(float4*)(AGf + (size_t)node * 128 + c4) = r;
}

// ---------------------------------------------------------------- split-bf16 MFMA GEMM, fp32 staging — 8-wave LDS version (R6 body, unchanged)
// LDS staging is ESSENTIAL (R5 lesson). K=256: steps 0-3 read fp32 agg,
// steps 4-7 read fp32 h; fsplit at staging. D = Ahi·Bhi + Ahi·Blo + Alo·Bhi.
// 128x128 tile, 8 waves (2M x 4N of 64x32), 512 threads. In-place safe.
__global__ __launch_bounds__(512) void k_gemm(const float* __restrict__ AGf,
                                              const float* __restrict__ Hsrc,
                                              const ushort* __restrict__ BTh,
                                              const ushort* __restrict__ BTl,
                                              const float* __restrict__ bl,
                                              float* __restrict__ Hout) {
    __shared__ short As[2][128][40];
    __shared__ short Bs[2][128][40];
    const int tid = threadIdx.x;
    const int wave = tid >> 6, lane = tid & 63;
    const int m0 = blockIdx.x * 128;
    const int wm = (wave & 1) * 64;        // 2 waves in M
    const int wn = (wave >> 1) * 32;       // 4 waves in N
    const int l15 = lane & 15, lk = (lane >> 4) * 8;

    const int sr = tid >> 2;               // 0..127 (row)
    const int sc = (tid & 3) * 8;          // 0,8,16,24 (k-col within 32-step)
    int garow = m0 + sr; if (garow >= N_NODES) garow = N_NODES - 1;
    const float*  pAg = AGf  + (size_t)garow * 128 + sc;
    const float*  pHf = Hsrc + (size_t)garow * 128 + sc;
    const ushort* pBh = BTh + sr * 256 + sc;
    const ushort* pBl = BTl + sr * 256 + sc;

    bfrag8 rBh, rBl;
    float4 f0, f1;
#define LOADSTEP(S) do { \
        const float* pa = ((S) < 4) ? pAg : pHf; \
        f0 = *(const float4*)(pa + ((S) & 3) * 32); \
        f1 = *(const float4*)(pa + ((S) & 3) * 32 + 4); \
        rBh = *(const bfrag8*)(pBh + (S) * 32); \
        rBl = *(const bfrag8*)(pBl + (S) * 32); \
    } while (0)

    LOADSTEP(0);
    facc4 acc[4][2] = {};
#pragma unroll
    for (int s = 0; s < 8; s++) {
        {
            float v[8] = {f0.x, f0.y, f0.z, f0.w, f1.x, f1.y, f1.z, f1.w};
            bfrag8 Hh, Ll;
#pragma unroll
            for (int i = 0; i < 8; i++) {
                ushort hh, ll;
                fsplit(v[i], hh, ll);
                Hh[i] = (short)hh; Ll[i] = (short)ll;
            }
            *(bfrag8*)&As[0][sr][sc] = Hh;
            *(bfrag8*)&As[1][sr][sc] = Ll;
        }
        *(bfrag8*)&Bs[0][sr][sc] = rBh;
        *(bfrag8*)&Bs[1][sr][sc] = rBl;
        __syncthreads();
        if (s < 7) LOADSTEP(s + 1);   // prefetch next K-step (overlaps MFMAs below)
        bfrag8 a[2][4], b[2][2];
#pragma unroll
        for (int t = 0; t < 4; t++) {
            a[0][t] = *(const bfrag8*)&As[0][wm + t * 16 + l15][lk];
            a[1][t] = *(const bfrag8*)&As[1][wm + t * 16 + l15][lk];
        }
#pragma unroll
        for (int t = 0; t < 2; t++) {
            b[0][t] = *(const bfrag8*)&Bs[0][wn + t * 16 + l15][lk];
            b[1][t] = *(const bfrag8*)&Bs[1][wn + t * 16 + l15][lk];
        }
#pragma unroll
        for (int mt = 0; mt < 4; mt++)
#pragma unroll
            for (int nt = 0; nt < 2; nt++) {
                acc[mt][nt] = __builtin_amdgcn_mfma_f32_16x16x32_bf16(a[0][mt], b[0][nt], acc[mt][nt], 0, 0, 0);
                acc[mt][nt] = __builtin_amdgcn_mfma_f32_16x16x32_bf16(a[0][mt], b[1][nt], acc[mt][nt], 0, 0, 0);
                acc[mt][nt] = __builtin_amdgcn_mfma_f32_16x16x32_bf16(a[1][mt], b[0][nt], acc[mt][nt], 0, 0, 0);
            }
        __syncthreads();
    }
#undef LOADSTEP

    // epilogue: bias + relu, write fp32 H
    const int r4 = (lane >> 4) * 4;
#pragma unroll
    for (int mt = 0; mt < 4; mt++) {
#pragma unroll
        for (int nt = 0; nt < 2; nt++) {
            int col = wn + nt * 16 + l15;
            float bias = bl[col];
#pragma unroll
            for (int r = 0; r < 4; r++) {
                int grow = m0 + wm + mt * 16 + r4 + r;
                if (grow < N_NODES) {
                    Hout[(size_t)grow * 128 + col] = fmaxf(acc[mt][nt][r] + bias, 0.f);
                }
            }
        }
    }
}

// ---------------------------------------------------------------- k_head: mean-pool + classifier fused (one block per graph)
__global__ __launch_bounds__(256) void k_head(const float* __restrict__ H,
                                              const int* __restrict__ gstart,
                                              const int* __restrict__ root,
                                              const float* __restrict__ wcls,
                                              const float* __restrict__ bcls,
                                              float* __restrict__ out) {
    __shared__ float gm[128];
    __shared__ float part[128];
    __shared__ float red[8];
    const int g = blockIdx.x, t = threadIdx.x;
    const int c = t & 127, p = t >> 7;
    int s = gstart[g], e = gstart[g + 1];
    float sum = 0.f;
    for (int n = s + p; n < e; n += 2) {
        sum += H[(size_t)n * 128 + c];
    }
    if (p) part[c] = sum;
    __syncthreads();
    if (!p) gm[c] = (sum + part[c]) / fmaxf((float)(e - s), 1.0f);
    __syncthreads();
    float v;
    if (t < 128) {
        v = H[(size_t)root[g] * 128 + t];
    } else {
        v = gm[t - 128];
    }
    float p0 = v * wcls[t];
    float p1 = v * wcls[256 + t];
#pragma unroll
    for (int off = 32; off; off >>= 1) {
        p0 += __shfl_down(p0, off);
        p1 += __shfl_down(p1, off);
    }
    int wid = t >> 6;
    if ((t & 63) == 0) { red[wid] = p0; red[4 + wid] = p1; }
    __syncthreads();
    if (t == 0) {
        out[g * 2 + 0] = red[0] + red[1] + red[2] + red[3] + bcls[0];
        out[g * 2 + 1] = red[4] + red[5] + red[6] + red[7] + bcls[1];
    }
}

// ---------------------------------------------------------------- launch
extern "C" void kernel_launch(void* const* d_in, const int* in_sizes, int n_in,
                              void* d_out, int out_size, void* d_ws, size_t ws_size,
                              hipStream_t stream) {
    const float* x = (const float*)d_in[0];
    const int* ei = (const int*)d_in[1];
    const int* src = ei;
    const int* tgt = ei + N_EDGES;
    const int* root = (const int*)d_in[2];
    const int* batch = (const int*)d_in[3];
    WPtrs wp;
    wp.wl[0] = (const float*)d_in[4];  wp.wr[0] = (const float*)d_in[6];
    wp.wl[1] = (const float*)d_in[7];  wp.wr[1] = (const float*)d_in[9];
    wp.wl[2] = (const float*)d_in[10]; wp.wr[2] = (const float*)d_in[12];
    wp.wl[3] = (const float*)d_in[13]; wp.wr[3] = (const float*)d_in[15];
    const float* blv[4] = {(const float*)d_in[5], (const float*)d_in[8],
                           (const float*)d_in[11], (const float*)d_in[14]};
    const float* wcls = (const float*)d_in[16];
    const float* bcls = (const float*)d_in[17];
    float* out = (float*)d_out;

    // workspace carve-up
    float* H = (float*)d_ws;                          // 50000*128 f32 (h plane)
    float* AGf = H + (size_t)N_NODES * 128;           // 50000*128 f32 (agg plane)
    ushort* BTh = (ushort*)(AGf + (size_t)N_NODES * 128); // 4*128*256
    ushort* BTl = BTh + 4 * 128 * 256;                // 4*128*256
    int* deg = (int*)(BTl + 4 * 128 * 256);           // 50000 (+fill adjacent)
    int* fill = deg + N_NODES;                        // 50000
    float* dinv = (float*)(fill + N_NODES);           // 50000
    int* rowptr = (int*)(dinv + N_NODES);             // 50001
    int* csr_src = rowptr + N_NODES + 1;              // 600000
    int* bsum = csr_src + N_EDGES;                    // 196
    int* gstart = bsum + 256;                         // 257
    (void)fill;

    // one cooperative launch replaces memset + prep + scan1 + scan2 + fill
    {
        void* args[] = {(void*)&src, (void*)&tgt, (void*)&deg, (void*)&wp,
                        (void*)&BTh, (void*)&BTl, (void*)&batch, (void*)&gstart,
                        (void*)&dinv, (void*)&rowptr, (void*)&csr_src, (void*)&bsum};
        hipLaunchCooperativeKernel((void*)k_build, dim3(BUILD_BLOCKS), dim3(256),
                                   args, 0, stream);
    }

    for (int l = 0; l < 4; l++) {
        const float* hsrc = (l == 0) ? x : H;
        k_gather<<<(N_NODES + 7) / 8, 256, 0, stream>>>(hsrc, AGf, csr_src, rowptr, dinv);
        k_gemm<<<(N_NODES + 127) / 128, 512, 0, stream>>>(
            AGf, hsrc, BTh + l * 32768, BTl + l * 32768, blv[l], H);
    }
    k_head<<<N_GRAPHS, 256, 0, stream>>>(H, gstart, root, wcls, bcls, out);
}

// Round 9
// 444.924 us; speedup vs baseline: 1.9253x; 1.9253x over previous
//
#include <hip/hip_runtime.h>

#define N_NODES 50000
#define N_EDGES 600000
#define N_GRAPHS 256
#define C 128
#define NB 196            // ceil(N_NODES/256) scan blocks
// k_prep block ranges
#define PB_DEG 2344       // ceil(600000/256)
#define PB_WS  512        // 131072/256

typedef unsigned short ushort;
typedef unsigned int uint;
typedef __attribute__((ext_vector_type(8))) short bfrag8;
typedef __attribute__((ext_vector_type(4))) float facc4;

// bf16 helpers (bit-level, RNE)
__device__ __forceinline__ ushort f2bf(float v) {
    uint u = __float_as_uint(v);
    u += 0x7FFFu + ((u >> 16) & 1u);
    return (ushort)(u >> 16);
}
__device__ __forceinline__ float bf2f(ushort u) {
    return __uint_as_float(((uint)u) << 16);
}
__device__ __forceinline__ void fsplit(float v, ushort& h, ushort& l) {
    h = f2bf(v);
    l = f2bf(v - bf2f(h));
}

struct WPtrs { const float* wl[4]; const float* wr[4]; };

// ---------------------------------------------------------------- k_prep: deg atomics + wsplit + gstart (range-partitioned)
// R8 lesson: grid.sync() costs ~100us on 8 XCDs — separate small launches
// beat any cooperative fusion here. Keep the 5-launch prep chain.
__global__ __launch_bounds__(256) void k_prep(const int* __restrict__ tgt,
                                              int* __restrict__ deg,
                                              WPtrs wp,
                                              ushort* __restrict__ BTh,
                                              ushort* __restrict__ BTl,
                                              const int* __restrict__ batch,
                                              int* __restrict__ gstart) {
    const int b = blockIdx.x, t = threadIdx.x;
    if (b < PB_DEG) {
        int e = b * 256 + t;
        if (e < N_EDGES) atomicAdd(&deg[tgt[e]], 1);
    } else if (b < PB_DEG + PB_WS) {
        int gid = (b - PB_DEG) * 256 + t;   // < 131072 exactly
        int l = gid >> 15;
        int rem = gid & 32767;
        int n = rem >> 8, k = rem & 255;
        float v = (k < 128) ? wp.wl[l][n * 128 + k] : wp.wr[l][n * 128 + (k - 128)];
        ushort h, lo;
        fsplit(v, h, lo);
        BTh[gid] = h;
        BTl[gid] = lo;
    } else {
        // gstart: g = t (0..255) binary search on sorted batch; plus sentinel
        int g = t;
        int lo = 0, hi = N_NODES;
        while (lo < hi) {
            int mid = (lo + hi) >> 1;
            if (batch[mid] < g) lo = mid + 1;
            else hi = mid;
        }
        gstart[g] = lo;
        if (t == 0) gstart[N_GRAPHS] = N_NODES;
    }
}

// ---------------------------------------------------------------- scan stage 1: block sums (+ dinv fused)
__global__ __launch_bounds__(256) void k_scan1(const int* __restrict__ deg,
                                               int* __restrict__ bsum,
                                               float* __restrict__ dinv) {
    __shared__ int ws[4];
    int idx = blockIdx.x * 256 + threadIdx.x;
    int v = (idx < N_NODES) ? deg[idx] : 0;
    if (idx < N_NODES) dinv[idx] = 1.0f / fmaxf((float)v, 1.0f);
    int s = v;
#pragma unroll
    for (int off = 1; off < 64; off <<= 1) s += __shfl_xor(s, off);
    if ((threadIdx.x & 63) == 0) ws[threadIdx.x >> 6] = s;
    __syncthreads();
    if (threadIdx.x == 0) bsum[blockIdx.x] = ws[0] + ws[1] + ws[2] + ws[3];
}

// ---------------------------------------------------------------- scan stage 2: global offset (recomputed per block) + local scan -> rowptr
__global__ __launch_bounds__(256) void k_scan2(const int* __restrict__ deg,
                                               const int* __restrict__ bsum,
                                               int* __restrict__ rowptr) {
    __shared__ int red[4];
    __shared__ int ws[4];
    const int b = blockIdx.x, t = threadIdx.x;
    const int lane = t & 63, w = t >> 6;
    int bv = (t < NB && t < b) ? bsum[t] : 0;
#pragma unroll
    for (int off = 1; off < 64; off <<= 1) bv += __shfl_xor(bv, off);
    if (lane == 0) red[w] = bv;
    __syncthreads();
    const int boff = red[0] + red[1] + red[2] + red[3];
    int idx = b * 256 + t;
    int v = (idx < N_NODES) ? deg[idx] : 0;
    int incl = v;
#pragma unroll
    for (int off = 1; off < 64; off <<= 1) {
        int u = __shfl_up(incl, off);
        if (lane >= off) incl += u;
    }
    if (lane == 63) ws[w] = incl;
    __syncthreads();
    int wo = 0;
    if (w > 0) wo += ws[0];
    if (w > 1) wo += ws[1];
    if (w > 2) wo += ws[2];
    if (idx < N_NODES) rowptr[idx] = boff + wo + incl - v;
    if (b == 0 && t == 0) rowptr[N_NODES] = N_EDGES;
}

// ---------------------------------------------------------------- CSR fill
__global__ void k_fill(const int* __restrict__ src, const int* __restrict__ tgt,
                       const int* __restrict__ rowptr, int* __restrict__ fill,
                       int* __restrict__ csr_src) {
    int e = blockIdx.x * blockDim.x + threadIdx.x;
    if (e >= N_EDGES) return;
    int d = tgt[e];
    int pos = atomicAdd(&fill[d], 1);
    csr_src[rowptr[d] + pos] = src[e];
}

// ---------------------------------------------------------------- gather-mean, monolithic fp32 — 8-edge unroll (MLP experiment)
// Counters (R2/R3/R6): 44% HBM peak, VALU 12%, occ 65%, FETCH pinned at
// 132 MB compulsory -> latency/MLP-bound, not BW-bound. 8 independent
// float4 loads in flight per lane (was 4) to fill the memory queue.
// If this doesn't move, the random-row pattern is memory-system floored.
__global__ __launch_bounds__(256) void k_gather(const float* __restrict__ Hsrc,
                                                float* __restrict__ AGf,
                                                const int* __restrict__ csr_src,
                                                const int* __restrict__ rowptr,
                                                const float* __restrict__ dinv) {
    int node = blockIdx.x * 8 + (threadIdx.x >> 5);
    if (node >= N_NODES) return;
    int lane = threadIdx.x & 31;
    int c4 = lane << 2;
    int s = rowptr[node], e = rowptr[node + 1];
    float sc = dinv[node];
    float a0 = 0.f, a1 = 0.f, a2 = 0.f, a3 = 0.f;
    int j = s;
    for (; j + 7 < e; j += 8) {
        int s0 = csr_src[j],     s1 = csr_src[j + 1];
        int s2 = csr_src[j + 2], s3 = csr_src[j + 3];
        int s4 = csr_src[j + 4], s5 = csr_src[j + 5];
        int s6 = csr_src[j + 6], s7 = csr_src[j + 7];
        float4 v0 = *(const float4*)(Hsrc + (size_t)s0 * 128 + c4);
        float4 v1 = *(const float4*)(Hsrc + (size_t)s1 * 128 + c4);
        float4 v2 = *(const float4*)(Hsrc + (size_t)s2 * 128 + c4);
        float4 v3 = *(const float4*)(Hsrc + (size_t)s3 * 128 + c4);
        float4 v4 = *(const float4*)(Hsrc + (size_t)s4 * 128 + c4);
        float4 v5 = *(const float4*)(Hsrc + (size_t)s5 * 128 + c4);
        float4 v6 = *(const float4*)(Hsrc + (size_t)s6 * 128 + c4);
        float4 v7 = *(const float4*)(Hsrc + (size_t)s7 * 128 + c4);
        a0 += ((v0.x + v1.x) + (v2.x + v3.x)) + ((v4.x + v5.x) + (v6.x + v7.x));
        a1 += ((v0.y + v1.y) + (v2.y + v3.y)) + ((v4.y + v5.y) + (v6.y + v7.y));
        a2 += ((v0.z + v1.z) + (v2.z + v3.z)) + ((v4.z + v5.z) + (v6.z + v7.z));
        a3 += ((v0.w + v1.w) + (v2.w + v3.w)) + ((v4.w + v5.w) + (v6.w + v7.w));
    }
    for (; j + 3 < e; j += 4) {
        int s0 = csr_src[j], s1 = csr_src[j + 1];
        int s2 = csr_src[j + 2], s3 = csr_src[j + 3];
        float4 v0 = *(const float4*)(Hsrc + (size_t)s0 * 128 + c4);
        float4 v1 = *(const float4*)(Hsrc + (size_t)s1 * 128 + c4);
        float4 v2 = *(const float4*)(Hsrc + (size_t)s2 * 128 + c4);
        float4 v3 = *(const float4*)(Hsrc + (size_t)s3 * 128 + c4);
        a0 += (v0.x + v1.x) + (v2.x + v3.x);
        a1 += (v0.y + v1.y) + (v2.y + v3.y);
        a2 += (v0.z + v1.z) + (v2.z + v3.z);
        a3 += (v0.w + v1.w) + (v2.w + v3.w);
    }
    for (; j < e; j++) {
        int s0 = csr_src[j];
        float4 v0 = *(const float4*)(Hsrc + (size_t)s0 * 128 + c4);
        a0 += v0.x; a1 += v0.y; a2 += v0.z; a3 += v0.w;
    }
    float4 r; r.x = a0 * sc; r.y = a1 * sc; r.z = a2 * sc; r.w = a3 * sc;
    *(float4*)(AGf + (size_t)node * 128 + c4) = r;
}

// ---------------------------------------------------------------- split-bf16 MFMA GEMM, fp32 staging — 8-wave LDS version (R6 body, unchanged)
// LDS staging is ESSENTIAL (R5 lesson). K=256: steps 0-3 read fp32 agg,
// steps 4-7 read fp32 h; fsplit at staging. D = Ahi·Bhi + Ahi·Blo + Alo·Bhi.
// 128x128 tile, 8 waves (2M x 4N of 64x32), 512 threads. In-place safe.
__global__ __launch_bounds__(512) void k_gemm(const float* __restrict__ AGf,
                                              const float* __restrict__ Hsrc,
                                              const ushort* __restrict__ BTh,
                                              const ushort* __restrict__ BTl,
                                              const float* __restrict__ bl,
                                              float* __restrict__ Hout) {
    __shared__ short As[2][128][40];
    __shared__ short Bs[2][128][40];
    const int tid = threadIdx.x;
    const int wave = tid >> 6, lane = tid & 63;
    const int m0 = blockIdx.x * 128;
    const int wm = (wave & 1) * 64;        // 2 waves in M
    const int wn = (wave >> 1) * 32;       // 4 waves in N
    const int l15 = lane & 15, lk = (lane >> 4) * 8;

    const int sr = tid >> 2;               // 0..127 (row)
    const int sc = (tid & 3) * 8;          // 0,8,16,24 (k-col within 32-step)
    int garow = m0 + sr; if (garow >= N_NODES) garow = N_NODES - 1;
    const float*  pAg = AGf  + (size_t)garow * 128 + sc;
    const float*  pHf = Hsrc + (size_t)garow * 128 + sc;
    const ushort* pBh = BTh + sr * 256 + sc;
    const ushort* pBl = BTl + sr * 256 + sc;

    bfrag8 rBh, rBl;
    float4 f0, f1;
#define LOADSTEP(S) do { \
        const float* pa = ((S) < 4) ? pAg : pHf; \
        f0 = *(const float4*)(pa + ((S) & 3) * 32); \
        f1 = *(const float4*)(pa + ((S) & 3) * 32 + 4); \
        rBh = *(const bfrag8*)(pBh + (S) * 32); \
        rBl = *(const bfrag8*)(pBl + (S) * 32); \
    } while (0)

    LOADSTEP(0);
    facc4 acc[4][2] = {};
#pragma unroll
    for (int s = 0; s < 8; s++) {
        {
            float v[8] = {f0.x, f0.y, f0.z, f0.w, f1.x, f1.y, f1.z, f1.w};
            bfrag8 Hh, Ll;
#pragma unroll
            for (int i = 0; i < 8; i++) {
                ushort hh, ll;
                fsplit(v[i], hh, ll);
                Hh[i] = (short)hh; Ll[i] = (short)ll;
            }
            *(bfrag8*)&As[0][sr][sc] = Hh;
            *(bfrag8*)&As[1][sr][sc] = Ll;
        }
        *(bfrag8*)&Bs[0][sr][sc] = rBh;
        *(bfrag8*)&Bs[1][sr][sc] = rBl;
        __syncthreads();
        if (s < 7) LOADSTEP(s + 1);   // prefetch next K-step (overlaps MFMAs below)
        bfrag8 a[2][4], b[2][2];
#pragma unroll
        for (int t = 0; t < 4; t++) {
            a[0][t] = *(const bfrag8*)&As[0][wm + t * 16 + l15][lk];
            a[1][t] = *(const bfrag8*)&As[1][wm + t * 16 + l15][lk];
        }
#pragma unroll
        for (int t = 0; t < 2; t++) {
            b[0][t] = *(const bfrag8*)&Bs[0][wn + t * 16 + l15][lk];
            b[1][t] = *(const bfrag8*)&Bs[1][wn + t * 16 + l15][lk];
        }
#pragma unroll
        for (int mt = 0; mt < 4; mt++)
#pragma unroll
            for (int nt = 0; nt < 2; nt++) {
                acc[mt][nt] = __builtin_amdgcn_mfma_f32_16x16x32_bf16(a[0][mt], b[0][nt], acc[mt][nt], 0, 0, 0);
                acc[mt][nt] = __builtin_amdgcn_mfma_f32_16x16x32_bf16(a[0][mt], b[1][nt], acc[mt][nt], 0, 0, 0);
                acc[mt][nt] = __builtin_amdgcn_mfma_f32_16x16x32_bf16(a[1][mt], b[0][nt], acc[mt][nt], 0, 0, 0);
            }
        __syncthreads();
    }
#undef LOADSTEP

    // epilogue: bias + relu, write fp32 H
    const int r4 = (lane >> 4) * 4;
#pragma unroll
    for (int mt = 0; mt < 4; mt++) {
#pragma unroll
        for (int nt = 0; nt < 2; nt++) {
            int col = wn + nt * 16 + l15;
            float bias = bl[col];
#pragma unroll
            for (int r = 0; r < 4; r++) {
                int grow = m0 + wm + mt * 16 + r4 + r;
                if (grow < N_NODES) {
                    Hout[(size_t)grow * 128 + col] = fmaxf(acc[mt][nt][r] + bias, 0.f);
                }
            }
        }
    }
}

// ---------------------------------------------------------------- k_head: mean-pool + classifier fused (one block per graph)
__global__ __launch_bounds__(256) void k_head(const float* __restrict__ H,
                                              const int* __restrict__ gstart,
                                              const int* __restrict__ root,
                                              const float* __restrict__ wcls,
                                              const float* __restrict__ bcls,
                                              float* __restrict__ out) {
    __shared__ float gm[128];
    __shared__ float part[128];
    __shared__ float red[8];
    const int g = blockIdx.x, t = threadIdx.x;
    const int c = t & 127, p = t >> 7;
    int s = gstart[g], e = gstart[g + 1];
    float sum = 0.f;
    for (int n = s + p; n < e; n += 2) {
        sum += H[(size_t)n * 128 + c];
    }
    if (p) part[c] = sum;
    __syncthreads();
    if (!p) gm[c] = (sum + part[c]) / fmaxf((float)(e - s), 1.0f);
    __syncthreads();
    float v;
    if (t < 128) {
        v = H[(size_t)root[g] * 128 + t];
    } else {
        v = gm[t - 128];
    }
    float p0 = v * wcls[t];
    float p1 = v * wcls[256 + t];
#pragma unroll
    for (int off = 32; off; off >>= 1) {
        p0 += __shfl_down(p0, off);
        p1 += __shfl_down(p1, off);
    }
    int wid = t >> 6;
    if ((t & 63) == 0) { red[wid] = p0; red[4 + wid] = p1; }
    __syncthreads();
    if (t == 0) {
        out[g * 2 + 0] = red[0] + red[1] + red[2] + red[3] + bcls[0];
        out[g * 2 + 1] = red[4] + red[5] + red[6] + red[7] + bcls[1];
    }
}

// ---------------------------------------------------------------- launch
extern "C" void kernel_launch(void* const* d_in, const int* in_sizes, int n_in,
                              void* d_out, int out_size, void* d_ws, size_t ws_size,
                              hipStream_t stream) {
    const float* x = (const float*)d_in[0];
    const int* ei = (const int*)d_in[1];
    const int* src = ei;
    const int* tgt = ei + N_EDGES;
    const int* root = (const int*)d_in[2];
    const int* batch = (const int*)d_in[3];
    WPtrs wp;
    wp.wl[0] = (const float*)d_in[4];  wp.wr[0] = (const float*)d_in[6];
    wp.wl[1] = (const float*)d_in[7];  wp.wr[1] = (const float*)d_in[9];
    wp.wl[2] = (const float*)d_in[10]; wp.wr[2] = (const float*)d_in[12];
    wp.wl[3] = (const float*)d_in[13]; wp.wr[3] = (const float*)d_in[15];
    const float* blv[4] = {(const float*)d_in[5], (const float*)d_in[8],
                           (const float*)d_in[11], (const float*)d_in[14]};
    const float* wcls = (const float*)d_in[16];
    const float* bcls = (const float*)d_in[17];
    float* out = (float*)d_out;

    // workspace carve-up
    float* H = (float*)d_ws;                          // 50000*128 f32 (h plane)
    float* AGf = H + (size_t)N_NODES * 128;           // 50000*128 f32 (agg plane)
    ushort* BTh = (ushort*)(AGf + (size_t)N_NODES * 128); // 4*128*256
    ushort* BTl = BTh + 4 * 128 * 256;                // 4*128*256
    int* deg = (int*)(BTl + 4 * 128 * 256);           // 50000
    int* fill = deg + N_NODES;                        // 50000 (adjacent: one memset)
    float* dinv = (float*)(fill + N_NODES);           // 50000
    int* rowptr = (int*)(dinv + N_NODES);             // 50001
    int* csr_src = rowptr + N_NODES + 1;              // 600000
    int* bsum = csr_src + N_EDGES;                    // 196
    int* gstart = bsum + 256;                         // 257

    hipMemsetAsync(deg, 0, 2 * N_NODES * sizeof(int), stream);  // deg + fill
    k_prep<<<PB_DEG + PB_WS + 1, 256, 0, stream>>>(
        tgt, deg, wp, BTh, BTl, batch, gstart);
    k_scan1<<<NB, 256, 0, stream>>>(deg, bsum, dinv);
    k_scan2<<<NB, 256, 0, stream>>>(deg, bsum, rowptr);
    k_fill<<<(N_EDGES + 255) / 256, 256, 0, stream>>>(src, tgt, rowptr, fill, csr_src);

    for (int l = 0; l < 4; l++) {
        const float* hsrc = (l == 0) ? x : H;
        k_gather<<<(N_NODES + 7) / 8, 256, 0, stream>>>(hsrc, AGf, csr_src, rowptr, dinv);
        k_gemm<<<(N_NODES + 127) / 128, 512, 0, stream>>>(
            AGf, hsrc, BTh + l * 32768, BTl + l * 32768, blv[l], H);
    }
    k_head<<<N_GRAPHS, 256, 0, stream>>>(H, gstart, root, wcls, bcls, out);
}